// Round 2
// baseline (5260.292 us; speedup 1.0000x reference)
//
#include <hip/hip_runtime.h>
#include <hip/hip_bf16.h>
#include <stdint.h>

#define T_STEPS 2048
#define BATCH   256
#define IDIM    128
#define HDIM    128

typedef __bf16 bf16x2 __attribute__((ext_vector_type(2)));

#if __has_builtin(__builtin_amdgcn_fdot2_f32_bf16)
#define HAVE_DOT2 1
#else
#define HAVE_DOT2 0
#endif

static __device__ __forceinline__ float d2(uint32_t a, uint32_t b, float c) {
#if HAVE_DOT2
  return __builtin_amdgcn_fdot2_f32_bf16(__builtin_bit_cast(bf16x2, a),
                                         __builtin_bit_cast(bf16x2, b), c, false);
#else
  float alo = __builtin_bit_cast(float, a << 16);
  float ahi = __builtin_bit_cast(float, a & 0xffff0000u);
  float blo = __builtin_bit_cast(float, b << 16);
  float bhi = __builtin_bit_cast(float, b & 0xffff0000u);
  return c + alo * blo + ahi * bhi;
#endif
}

static __device__ __forceinline__ uint32_t pack_bf16(float lo, float hi) {
  uint32_t a = (uint32_t)__builtin_bit_cast(unsigned short, __float2bfloat16(lo));
  uint32_t b = (uint32_t)__builtin_bit_cast(unsigned short, __float2bfloat16(hi));
  return a | (b << 16);
}

static __device__ __forceinline__ float sigmoidf_(float x) {
  return 1.f / (1.f + __expf(-x));
}
static __device__ __forceinline__ float tanhf_(float x) {
  // 1 - 2/(1+e^{2x}): saturates correctly at +-inf (no NaN)
  return 1.f - 2.f / (1.f + __expf(2.f * x));
}

// ---------------------------------------------------------------------------
// Weight packing: wpack[((m*4+q)*128 + j)*16 + p] = bf16 pair of
// W_m[i][j], W_m[i+1][j] with i = 32q + 2p.  12 matrices of 128x128.
// m: 0=Wz0 1=Wr0 2=Wh0 3=Uz0 4=Ur0 5=Uh0 6=Uz1 7=Ur1 8=Wz1 9=Wr1 10=Wh1 11=Uh1
// ---------------------------------------------------------------------------
__global__ void pack_weights(const float* __restrict__ Wz, const float* __restrict__ Uz,
                             const float* __restrict__ Wr, const float* __restrict__ Ur,
                             const float* __restrict__ Wh, const float* __restrict__ Uh,
                             uint32_t* __restrict__ wpack) {
  int idx = blockIdx.x * blockDim.x + threadIdx.x;
  if (idx >= 12 * 4 * 128 * 16) return;
  int p = idx & 15;
  int j = (idx >> 4) & 127;
  int q = (idx >> 11) & 3;
  int m = idx >> 13;
  const float* src;
  switch (m) {
    case 0:  src = Wz;          break;
    case 1:  src = Wr;          break;
    case 2:  src = Wh;          break;
    case 3:  src = Uz;          break;
    case 4:  src = Ur;          break;
    case 5:  src = Uh;          break;
    case 6:  src = Uz + 16384;  break;
    case 7:  src = Ur + 16384;  break;
    case 8:  src = Wz + 16384;  break;
    case 9:  src = Wr + 16384;  break;
    case 10: src = Wh + 16384;  break;
    default: src = Uh + 16384;  break;
  }
  int i = q * 32 + p * 2;
  float lo = src[i * 128 + j];
  float hi = src[(i + 1) * 128 + j];
  wpack[idx] = pack_bf16(lo, hi);
}

// ---------------------------------------------------------------------------
// Persistent GRU kernel: 1 block = 1 batch element, 512 threads (8 waves).
// Thread t owns quarter-column (j = t&127, q = t>>7) of all 12 matrices in
// registers (192 VGPRs of packed bf16).  h-state fp32 in LDS; matvec inputs
// packed to bf16 pairs each step; fp32 accumulation via v_dot2_f32_bf16.
// ---------------------------------------------------------------------------
#define QD(M)                                                          \
  {                                                                    \
    float a0 = 0.f, a1 = 0.f;                                          \
    a0 = d2(w[M][0].x, v0.x, a0); a0 = d2(w[M][0].y, v0.y, a0);        \
    a0 = d2(w[M][0].z, v0.z, a0); a0 = d2(w[M][0].w, v0.w, a0);        \
    a0 = d2(w[M][1].x, v1.x, a0); a0 = d2(w[M][1].y, v1.y, a0);        \
    a0 = d2(w[M][1].z, v1.z, a0); a0 = d2(w[M][1].w, v1.w, a0);        \
    a1 = d2(w[M][2].x, v2.x, a1); a1 = d2(w[M][2].y, v2.y, a1);        \
    a1 = d2(w[M][2].z, v2.z, a1); a1 = d2(w[M][2].w, v2.w, a1);        \
    a1 = d2(w[M][3].x, v3.x, a1); a1 = d2(w[M][3].y, v3.y, a1);        \
    a1 = d2(w[M][3].z, v3.z, a1); a1 = d2(w[M][3].w, v3.w, a1);        \
    part[(M * 4 + q) * 128 + j] = a0 + a1;                             \
  }

#define LOADV(VB)                                                      \
  const uint4* vp = (const uint4*)(VB);                                \
  uint4 v0 = vp[q * 4 + 0], v1 = vp[q * 4 + 1],                        \
        v2 = vp[q * 4 + 2], v3 = vp[q * 4 + 3];

#define PSUM(M)                                                        \
  ((part[(M * 4 + 0) * 128 + j2] + part[(M * 4 + 1) * 128 + j2]) +     \
   (part[(M * 4 + 2) * 128 + j2] + part[(M * 4 + 3) * 128 + j2]))

static __device__ __forceinline__ void pair_store(uint32_t* dst, int j2, float v) {
  uint32_t me = (uint32_t)__builtin_bit_cast(unsigned short, __float2bfloat16(v));
  uint32_t other = __shfl_xor((unsigned int)me, 1, 64);
  if ((j2 & 1) == 0) dst[j2 >> 1] = me | (other << 16);
}

__launch_bounds__(512, 2)
__global__ void gru_persist(const float* __restrict__ x,
                            const float* __restrict__ bz, const float* __restrict__ br,
                            const float* __restrict__ bh,
                            const float* __restrict__ fcw, const float* __restrict__ fcb,
                            const uint32_t* __restrict__ wpack,
                            float* __restrict__ out) {
  __shared__ float part[12 * 4 * 128];                 // 24 KB partial dots
  __shared__ float h0f[128], h1f[128], z0f[128], z1f[128];
  __shared__ uint32_t xbf[64], h0bf[64], h1bf[64], rh0bf[64], rh1bf[64];
  __shared__ float biasL[6 * 128];

  const int tid = threadIdx.x;
  const int j = tid & 127;
  const int q = tid >> 7;
  const int b = blockIdx.x;

  // --- weights into registers (fully static indexing) ---
  uint4 w[12][4];
  {
    const uint4* wp4 = (const uint4*)wpack;
#pragma unroll
    for (int m = 0; m < 12; ++m)
#pragma unroll
      for (int p = 0; p < 4; ++p)
        w[m][p] = wp4[((m * 4 + q) * 128 + j) * 4 + p];
  }

  // --- init state / biases / first x row ---
  if (tid < 128) {
    h0f[tid] = 0.f; h1f[tid] = 0.f;
    biasL[0 * 128 + tid] = bz[tid];
    biasL[1 * 128 + tid] = br[tid];
    biasL[2 * 128 + tid] = bh[tid];
    biasL[3 * 128 + tid] = bz[128 + tid];
    biasL[4 * 128 + tid] = br[128 + tid];
    biasL[5 * 128 + tid] = bh[128 + tid];
  }
  if (tid < 64) { h0bf[tid] = 0u; h1bf[tid] = 0u; }
  const float2* xrow = (const float2*)(x + (size_t)b * T_STEPS * IDIM);
  if (tid < 64) {
    float2 v = xrow[tid];  // t = 0
    xbf[tid] = pack_bf16(v.x, v.y);
  }
  __syncthreads();

  float2 xpre = make_float2(0.f, 0.f);
  for (int t = 0; t < T_STEPS; ++t) {
    // prefetch next timestep's x slice (clamped at the end)
    if (tid < 64) {
      int tn = (t + 1 < T_STEPS) ? (t + 1) : t;
      xpre = xrow[tn * 64 + tid];
    }

    // ---- phase A: x@{Wz0,Wr0,Wh0}, h0@{Uz0,Ur0}, h1@{Uz1,Ur1} ----
    { LOADV(xbf);  QD(0); QD(1); QD(2); }
    { LOADV(h0bf); QD(3); QD(4); }
    { LOADV(h1bf); QD(6); QD(7); }
    __syncthreads();

    // ---- gates z0, r0 ----
    if (tid < 128) {
      const int j2 = tid;
      float az = biasL[0 * 128 + j2] + PSUM(0) + PSUM(3);
      float ar = biasL[1 * 128 + j2] + PSUM(1) + PSUM(4);
      float z = sigmoidf_(az);
      float r = sigmoidf_(ar);
      z0f[j2] = z;
      pair_store(rh0bf, j2, r * h0f[j2]);
    }
    __syncthreads();

    // ---- phase B: (r0*h0)@Uh0 ----
    { LOADV(rh0bf); QD(5); }
    __syncthreads();

    // ---- h~0, blend, new h0 ----
    if (tid < 128) {
      const int j2 = tid;
      float ah = biasL[2 * 128 + j2] + PSUM(2) + PSUM(5);
      float ht = tanhf_(ah);
      float z = z0f[j2];
      float hn = (1.f - z) * h0f[j2] + z * ht;
      h0f[j2] = hn;
      pair_store(h0bf, j2, hn);
    }
    __syncthreads();

    // ---- phase C: h0new@{Wz1,Wr1,Wh1} ----
    { LOADV(h0bf); QD(8); QD(9); QD(10); }
    __syncthreads();

    // ---- gates z1, r1 ----
    if (tid < 128) {
      const int j2 = tid;
      float az = biasL[3 * 128 + j2] + PSUM(8) + PSUM(6);
      float ar = biasL[4 * 128 + j2] + PSUM(9) + PSUM(7);
      float z = sigmoidf_(az);
      float r = sigmoidf_(ar);
      z1f[j2] = z;
      pair_store(rh1bf, j2, r * h1f[j2]);
    }
    __syncthreads();

    // ---- phase D: (r1*h1)@Uh1 ----
    { LOADV(rh1bf); QD(11); }
    __syncthreads();

    // ---- h~1, blend, new h1; stage next x ----
    if (tid < 128) {
      const int j2 = tid;
      float ah = biasL[5 * 128 + j2] + PSUM(10) + PSUM(11);
      float ht = tanhf_(ah);
      float z = z1f[j2];
      float hn = (1.f - z) * h1f[j2] + z * ht;
      h1f[j2] = hn;
      pair_store(h1bf, j2, hn);
    }
    if (tid < 64) xbf[tid] = pack_bf16(xpre.x, xpre.y);
    __syncthreads();
  }

  // ---- epilogue: out[b] = h1 . fc_w + fc_b ----
  if (tid < 128) part[tid] = h1f[tid] * fcw[tid];
  __syncthreads();
  if (tid == 0) {
    float s = fcb[0];
#pragma unroll 8
    for (int i = 0; i < 128; ++i) s += part[i];
    out[b] = s;
  }
}

extern "C" void kernel_launch(void* const* d_in, const int* in_sizes, int n_in,
                              void* d_out, int out_size, void* d_ws, size_t ws_size,
                              hipStream_t stream) {
  const float* x   = (const float*)d_in[0];
  const float* Wz  = (const float*)d_in[1];
  const float* bz  = (const float*)d_in[2];
  const float* Uz  = (const float*)d_in[3];
  const float* Wr  = (const float*)d_in[4];
  const float* br  = (const float*)d_in[5];
  const float* Ur  = (const float*)d_in[6];
  const float* Wh  = (const float*)d_in[7];
  const float* bh  = (const float*)d_in[8];
  const float* Uh  = (const float*)d_in[9];
  const float* fcw = (const float*)d_in[10];
  const float* fcb = (const float*)d_in[11];
  uint32_t* wpack = (uint32_t*)d_ws;  // 384 KB

  hipLaunchKernelGGL(pack_weights, dim3(384), dim3(256), 0, stream,
                     Wz, Uz, Wr, Ur, Wh, Uh, wpack);
  hipLaunchKernelGGL(gru_persist, dim3(BATCH), dim3(512), 0, stream,
                     x, bz, br, bh, fcw, fcb, wpack, (float*)d_out);
}

// Round 4
// 5056.832 us; speedup vs baseline: 1.0402x; 1.0402x over previous
//
#include <hip/hip_runtime.h>
#include <hip/hip_bf16.h>
#include <stdint.h>

#define T_STEPS 2048
#define BATCH   256
#define IDIM    128
#define HDIM    128

typedef __bf16 bf16x2 __attribute__((ext_vector_type(2)));

#if __has_builtin(__builtin_amdgcn_fdot2_f32_bf16)
#define HAVE_DOT2 1
#else
#define HAVE_DOT2 0
#endif

static __device__ __forceinline__ float d2(uint32_t a, uint32_t b, float c) {
#if HAVE_DOT2
  return __builtin_amdgcn_fdot2_f32_bf16(__builtin_bit_cast(bf16x2, a),
                                         __builtin_bit_cast(bf16x2, b), c, false);
#else
  float alo = __builtin_bit_cast(float, a << 16);
  float ahi = __builtin_bit_cast(float, a & 0xffff0000u);
  float blo = __builtin_bit_cast(float, b << 16);
  float bhi = __builtin_bit_cast(float, b & 0xffff0000u);
  return c + alo * blo + ahi * bhi;
#endif
}

static __device__ __forceinline__ uint32_t pack_bf16(float lo, float hi) {
  uint32_t a = (uint32_t)__builtin_bit_cast(unsigned short, __float2bfloat16(lo));
  uint32_t b = (uint32_t)__builtin_bit_cast(unsigned short, __float2bfloat16(hi));
  return a | (b << 16);
}
static __device__ __forceinline__ unsigned short bf16bits(float v) {
  return __builtin_bit_cast(unsigned short, __float2bfloat16(v));
}
static __device__ __forceinline__ float sigmoidf_(float x) {
  return 1.f / (1.f + __expf(-x));
}
static __device__ __forceinline__ float tanhf_(float x) {
  return 1.f - 2.f / (1.f + __expf(2.f * x));  // saturates, no NaN
}

// ===========================================================================
// NEW PATH: prepass (x-projections) + 9-matrix recurrent kernel
// wpackU layout: [((m*4+q)*128 + j)*16 + p] = pair W_m[i][j],W_m[i+1][j],
//   i = q*32 + 2p.  m: 0=Uz0 1=Ur0 2=Uh0 3=Wz1 4=Wr1 5=Wh1 6=Uz1 7=Ur1 8=Uh1
// wpackP layout: [c*64 + p] = pair Wg0[2p][j],Wg0[2p+1][j], c=g*128+j,
//   g: 0=Wz0 1=Wr0 2=Wh0
// ===========================================================================
#define NWU (9 * 4 * 128 * 16)   // 73728 words, 288 KB
#define NWP (384 * 64)           // 24576 words, 96 KB

__global__ void pack2(const float* __restrict__ Wz, const float* __restrict__ Uz,
                      const float* __restrict__ Wr, const float* __restrict__ Ur,
                      const float* __restrict__ Wh, const float* __restrict__ Uh,
                      uint32_t* __restrict__ wpackU, uint32_t* __restrict__ wpackP) {
  int idx = blockIdx.x * blockDim.x + threadIdx.x;
  if (idx < NWU) {
    int p = idx & 15;
    int j = (idx >> 4) & 127;
    int q = (idx >> 11) & 3;
    int m = idx >> 13;
    const float* src;
    switch (m) {
      case 0:  src = Uz;          break;
      case 1:  src = Ur;          break;
      case 2:  src = Uh;          break;
      case 3:  src = Wz + 16384;  break;
      case 4:  src = Wr + 16384;  break;
      case 5:  src = Wh + 16384;  break;
      case 6:  src = Uz + 16384;  break;
      case 7:  src = Ur + 16384;  break;
      default: src = Uh + 16384;  break;
    }
    int i = q * 32 + p * 2;
    wpackU[idx] = pack_bf16(src[i * 128 + j], src[(i + 1) * 128 + j]);
  } else if (idx < NWU + NWP) {
    int k = idx - NWU;
    int p = k & 63;
    int c = k >> 6;            // 0..383
    int g = c >> 7;
    int j = c & 127;
    const float* src = (g == 0) ? Wz : (g == 1) ? Wr : Wh;  // layer 0
    wpackP[k] = pack_bf16(src[2 * p * 128 + j], src[(2 * p + 1) * 128 + j]);
  }
}

// ---------------------------------------------------------------------------
// Prepass: proj[r][c] = x[r,:] . Wg0[:,j] + bias_g[j],  r = b*T+t, c = g*128+j
// 1024 blocks x 384 threads; 512 rows/block; column weights in registers.
// ---------------------------------------------------------------------------
template <int MODE>  // 0 = fp32 proj, 1 = bf16 proj
__global__ void xproj(const float* __restrict__ x,
                      const float* __restrict__ bz, const float* __restrict__ br,
                      const float* __restrict__ bh,
                      const uint32_t* __restrict__ wpackP, void* __restrict__ proj) {
  __shared__ uint32_t xs[64];
  const int c = threadIdx.x;       // 0..383
  const int g = c >> 7;
  const int j = c & 127;
  uint32_t wc[64];
#pragma unroll
  for (int p = 0; p < 64; ++p) wc[p] = wpackP[c * 64 + p];
  const float bias = ((g == 0) ? bz : (g == 1) ? br : bh)[j];

  const long r0 = (long)blockIdx.x * 512;
  for (int rr = 0; rr < 512; ++rr) {
    const long r = r0 + rr;
    if (c < 64) {
      float2 v = ((const float2*)(x + r * 128))[c];
      xs[c] = pack_bf16(v.x, v.y);
    }
    __syncthreads();
    float acc = bias;
#pragma unroll
    for (int p = 0; p < 64; ++p) acc = d2(wc[p], xs[p], acc);
    if (MODE == 0)
      ((float*)proj)[r * 384 + c] = acc;
    else
      ((unsigned short*)proj)[r * 384 + c] = bf16bits(acc);
    __syncthreads();
  }
}

// ---------------------------------------------------------------------------
// Recurrent kernel: 1 block = 1 batch element, 512 threads, 9 matrices
// register-resident (144 VGPRs, asm-pinned against rematerialization).
// ---------------------------------------------------------------------------
#define QD(M)                                                          \
  {                                                                    \
    float a0 = 0.f, a1 = 0.f;                                          \
    a0 = d2(w[M][0].x, v0.x, a0); a0 = d2(w[M][0].y, v0.y, a0);        \
    a0 = d2(w[M][0].z, v0.z, a0); a0 = d2(w[M][0].w, v0.w, a0);        \
    a0 = d2(w[M][1].x, v1.x, a0); a0 = d2(w[M][1].y, v1.y, a0);        \
    a0 = d2(w[M][1].z, v1.z, a0); a0 = d2(w[M][1].w, v1.w, a0);        \
    a1 = d2(w[M][2].x, v2.x, a1); a1 = d2(w[M][2].y, v2.y, a1);        \
    a1 = d2(w[M][2].z, v2.z, a1); a1 = d2(w[M][2].w, v2.w, a1);        \
    a1 = d2(w[M][3].x, v3.x, a1); a1 = d2(w[M][3].y, v3.y, a1);        \
    a1 = d2(w[M][3].z, v3.z, a1); a1 = d2(w[M][3].w, v3.w, a1);        \
    part[(M * 4 + q) * 128 + j] = a0 + a1;                             \
  }

#define LOADV(VB)                                                      \
  const uint4* vp = (const uint4*)(VB);                                \
  uint4 v0 = vp[q * 4 + 0], v1 = vp[q * 4 + 1],                        \
        v2 = vp[q * 4 + 2], v3 = vp[q * 4 + 3];

#define PSUM(M)                                                        \
  ((part[(M * 4 + 0) * 128 + j2] + part[(M * 4 + 1) * 128 + j2]) +     \
   (part[(M * 4 + 2) * 128 + j2] + part[(M * 4 + 3) * 128 + j2]))

template <int MODE>  // 0 = fp32 proj, 1 = bf16 proj
__launch_bounds__(512, 2)
__global__ void gru_persist2(const void* __restrict__ proj,
                             const float* __restrict__ bz1, const float* __restrict__ br1,
                             const float* __restrict__ bh1,
                             const float* __restrict__ fcw, const float* __restrict__ fcb,
                             const uint32_t* __restrict__ wpackU,
                             float* __restrict__ out) {
  __shared__ float part[9 * 4 * 128];                    // 18 KB
  __shared__ float h0f[128], h1f[128], z0f[128];
  __shared__ __align__(16) uint32_t h0bf[64], h1bf[64], rh0bf[64], rh1bf[64];
  __shared__ float pbuf[384];
  __shared__ float biasL[3 * 128];

  const int tid = threadIdx.x;
  const int j = tid & 127;
  const int q = tid >> 7;
  const int b = blockIdx.x;

  // --- weights into registers, pinned (cannot be rematerialized) ---
  uint4 w[9][4];
  {
    const uint4* wp4 = (const uint4*)wpackU;
#pragma unroll
    for (int m = 0; m < 9; ++m)
#pragma unroll
      for (int p = 0; p < 4; ++p)
        w[m][p] = wp4[((m * 4 + q) * 128 + j) * 4 + p];
  }
#pragma unroll
  for (int m = 0; m < 9; ++m)
#pragma unroll
    for (int p = 0; p < 4; ++p)
      asm volatile("" : "+v"(w[m][p].x), "+v"(w[m][p].y),
                        "+v"(w[m][p].z), "+v"(w[m][p].w));

  if (tid < 128) {
    h0f[tid] = 0.f; h1f[tid] = 0.f;
    biasL[0 * 128 + tid] = bz1[tid];
    biasL[1 * 128 + tid] = br1[tid];
    biasL[2 * 128 + tid] = bh1[tid];
  }
  if (tid < 64) { h0bf[tid] = 0u; h1bf[tid] = 0u; }

  // proj row pointers + first-row prefetch
  const float*    prow32 = (const float*)proj + (size_t)b * T_STEPS * 384;
  const uint32_t* prow16 = (const uint32_t*)proj + (size_t)b * T_STEPS * 192;
  float    pc32 = 0.f;
  uint32_t pc16 = 0u;
  if (MODE == 0) { if (tid < 384) pc32 = prow32[tid]; }
  else           { if (tid < 192) pc16 = prow16[tid]; }
  __syncthreads();

  for (int t = 0; t < T_STEPS; ++t) {
    // prefetch next step's proj row (latency hidden under this whole step)
    float pn32 = 0.f; uint32_t pn16 = 0u;
    {
      const int tn = (t + 1 < T_STEPS) ? (t + 1) : t;
      if (MODE == 0) { if (tid < 384) pn32 = prow32[(size_t)tn * 384 + tid]; }
      else           { if (tid < 192) pn16 = prow16[(size_t)tn * 192 + tid]; }
    }

    // ---- phase A: h0@{Uz0,Ur0}, h1@{Uz1,Ur1} ----
    { LOADV(h0bf); QD(0); QD(1); }
    { LOADV(h1bf); QD(6); QD(7); }
    // stage current proj row into LDS
    if (MODE == 0) {
      if (tid < 384) pbuf[tid] = pc32;
    } else {
      if (tid < 192) {
        pbuf[2 * tid]     = __builtin_bit_cast(float, pc16 << 16);
        pbuf[2 * tid + 1] = __builtin_bit_cast(float, pc16 & 0xffff0000u);
      }
    }
    __syncthreads();

    // ---- gates z0 (tid<128), r0 (128<=tid<256) ----
    if (tid < 256) {
      const int j2 = tid & 127;
      const bool isz = tid < 128;
      const int M = isz ? 0 : 1;
      float a = pbuf[(isz ? 0 : 128) + j2] + PSUM(M);
      float gv = sigmoidf_(a);
      if (isz) z0f[j2] = gv;
      else     ((unsigned short*)rh0bf)[j2] = bf16bits(gv * h0f[j2]);
    }
    __syncthreads();

    // ---- phase B: (r0*h0)@Uh0 ----
    { LOADV(rh0bf); QD(2); }
    __syncthreads();

    // ---- h~0, blend, new h0 ----
    if (tid < 128) {
      const int j2 = tid;
      float a = pbuf[256 + j2] + PSUM(2);
      float ht = tanhf_(a);
      float h = h0f[j2];
      float hn = fmaf(z0f[j2], ht - h, h);
      h0f[j2] = hn;
      ((unsigned short*)h0bf)[j2] = bf16bits(hn);
    }
    __syncthreads();

    // ---- phase C: h0new@{Wz1,Wr1,Wh1} ----
    { LOADV(h0bf); QD(3); QD(4); QD(5); }
    __syncthreads();

    // ---- gates z1, r1 ----
    if (tid < 256) {
      const int j2 = tid & 127;
      const bool isz = tid < 128;
      float a = isz ? (biasL[j2]       + PSUM(3) + PSUM(6))
                    : (biasL[128 + j2] + PSUM(4) + PSUM(7));
      float gv = sigmoidf_(a);
      if (isz) z0f[j2] = gv;   // reuse z0f slot for z1
      else     ((unsigned short*)rh1bf)[j2] = bf16bits(gv * h1f[j2]);
    }
    __syncthreads();

    // ---- phase D: (r1*h1)@Uh1 ----
    { LOADV(rh1bf); QD(8); }
    __syncthreads();

    // ---- h~1, blend, new h1 ----
    if (tid < 128) {
      const int j2 = tid;
      float a = biasL[256 + j2] + PSUM(5) + PSUM(8);
      float ht = tanhf_(a);
      float h = h1f[j2];
      float hn = fmaf(z0f[j2], ht - h, h);
      h1f[j2] = hn;
      ((unsigned short*)h1bf)[j2] = bf16bits(hn);
    }
    __syncthreads();

    pc32 = pn32; pc16 = pn16;
  }

  // ---- epilogue: out[b] = h1 . fc_w + fc_b ----
  if (tid < 128) part[tid] = h1f[tid] * fcw[tid];
  __syncthreads();
  if (tid == 0) {
    float s = fcb[0];
#pragma unroll 8
    for (int i = 0; i < 128; ++i) s += part[i];
    out[b] = s;
  }
}

// ===========================================================================
// FALLBACK PATH (round-2 kernel, verbatim; used only if ws too small)
// ===========================================================================
__global__ void pack_weights(const float* __restrict__ Wz, const float* __restrict__ Uz,
                             const float* __restrict__ Wr, const float* __restrict__ Ur,
                             const float* __restrict__ Wh, const float* __restrict__ Uh,
                             uint32_t* __restrict__ wpack) {
  int idx = blockIdx.x * blockDim.x + threadIdx.x;
  if (idx >= 12 * 4 * 128 * 16) return;
  int p = idx & 15;
  int j = (idx >> 4) & 127;
  int q = (idx >> 11) & 3;
  int m = idx >> 13;
  const float* src;
  switch (m) {
    case 0:  src = Wz;          break;
    case 1:  src = Wr;          break;
    case 2:  src = Wh;          break;
    case 3:  src = Uz;          break;
    case 4:  src = Ur;          break;
    case 5:  src = Uh;          break;
    case 6:  src = Uz + 16384;  break;
    case 7:  src = Ur + 16384;  break;
    case 8:  src = Wz + 16384;  break;
    case 9:  src = Wr + 16384;  break;
    case 10: src = Wh + 16384;  break;
    default: src = Uh + 16384;  break;
  }
  int i = q * 32 + p * 2;
  wpack[idx] = pack_bf16(src[i * 128 + j], src[(i + 1) * 128 + j]);
}

static __device__ __forceinline__ void pair_store(uint32_t* dst, int j2, float v) {
  uint32_t me = (uint32_t)bf16bits(v);
  uint32_t other = __shfl_xor((unsigned int)me, 1, 64);
  if ((j2 & 1) == 0) dst[j2 >> 1] = me | (other << 16);
}

__launch_bounds__(512, 2)
__global__ void gru_persist(const float* __restrict__ x,
                            const float* __restrict__ bz, const float* __restrict__ br,
                            const float* __restrict__ bh,
                            const float* __restrict__ fcw, const float* __restrict__ fcb,
                            const uint32_t* __restrict__ wpack,
                            float* __restrict__ out) {
  __shared__ float part[12 * 4 * 128];
  __shared__ float h0f[128], h1f[128], z0f[128], z1f[128];
  __shared__ __align__(16) uint32_t xbf[64], h0bf[64], h1bf[64], rh0bf[64], rh1bf[64];
  __shared__ float biasL[6 * 128];

  const int tid = threadIdx.x;
  const int j = tid & 127;
  const int q = tid >> 7;
  const int b = blockIdx.x;

  uint4 w[12][4];
  {
    const uint4* wp4 = (const uint4*)wpack;
#pragma unroll
    for (int m = 0; m < 12; ++m)
#pragma unroll
      for (int p = 0; p < 4; ++p)
        w[m][p] = wp4[((m * 4 + q) * 128 + j) * 4 + p];
  }

  if (tid < 128) {
    h0f[tid] = 0.f; h1f[tid] = 0.f;
    biasL[0 * 128 + tid] = bz[tid];
    biasL[1 * 128 + tid] = br[tid];
    biasL[2 * 128 + tid] = bh[tid];
    biasL[3 * 128 + tid] = bz[128 + tid];
    biasL[4 * 128 + tid] = br[128 + tid];
    biasL[5 * 128 + tid] = bh[128 + tid];
  }
  if (tid < 64) { h0bf[tid] = 0u; h1bf[tid] = 0u; }
  const float2* xrow = (const float2*)(x + (size_t)b * T_STEPS * IDIM);
  if (tid < 64) {
    float2 v = xrow[tid];
    xbf[tid] = pack_bf16(v.x, v.y);
  }
  __syncthreads();

  float2 xpre = make_float2(0.f, 0.f);
  for (int t = 0; t < T_STEPS; ++t) {
    if (tid < 64) {
      int tn = (t + 1 < T_STEPS) ? (t + 1) : t;
      xpre = xrow[tn * 64 + tid];
    }
    { LOADV(xbf);  QD(0); QD(1); QD(2); }
    { LOADV(h0bf); QD(3); QD(4); }
    { LOADV(h1bf); QD(6); QD(7); }
    __syncthreads();
    if (tid < 128) {
      const int j2 = tid;
      float az = biasL[0 * 128 + j2] + PSUM(0) + PSUM(3);
      float ar = biasL[1 * 128 + j2] + PSUM(1) + PSUM(4);
      float z = sigmoidf_(az);
      float r = sigmoidf_(ar);
      z0f[j2] = z;
      pair_store(rh0bf, j2, r * h0f[j2]);
    }
    __syncthreads();
    { LOADV(rh0bf); QD(5); }
    __syncthreads();
    if (tid < 128) {
      const int j2 = tid;
      float ah = biasL[2 * 128 + j2] + PSUM(2) + PSUM(5);
      float ht = tanhf_(ah);
      float z = z0f[j2];
      float hn = (1.f - z) * h0f[j2] + z * ht;
      h0f[j2] = hn;
      pair_store(h0bf, j2, hn);
    }
    __syncthreads();
    { LOADV(h0bf); QD(8); QD(9); QD(10); }
    __syncthreads();
    if (tid < 128) {
      const int j2 = tid;
      float az = biasL[3 * 128 + j2] + PSUM(8) + PSUM(6);
      float ar = biasL[4 * 128 + j2] + PSUM(9) + PSUM(7);
      float z = sigmoidf_(az);
      float r = sigmoidf_(ar);
      z1f[j2] = z;
      pair_store(rh1bf, j2, r * h1f[j2]);
    }
    __syncthreads();
    { LOADV(rh1bf); QD(11); }
    __syncthreads();
    if (tid < 128) {
      const int j2 = tid;
      float ah = biasL[5 * 128 + j2] + PSUM(10) + PSUM(11);
      float ht = tanhf_(ah);
      float z = z1f[j2];
      float hn = (1.f - z) * h1f[j2] + z * ht;
      h1f[j2] = hn;
      pair_store(h1bf, j2, hn);
    }
    if (tid < 64) xbf[tid] = pack_bf16(xpre.x, xpre.y);
    __syncthreads();
  }

  if (tid < 128) part[tid] = h1f[tid] * fcw[tid];
  __syncthreads();
  if (tid == 0) {
    float s = fcb[0];
#pragma unroll 8
    for (int i = 0; i < 128; ++i) s += part[i];
    out[b] = s;
  }
}

// ===========================================================================
extern "C" void kernel_launch(void* const* d_in, const int* in_sizes, int n_in,
                              void* d_out, int out_size, void* d_ws, size_t ws_size,
                              hipStream_t stream) {
  const float* x   = (const float*)d_in[0];
  const float* Wz  = (const float*)d_in[1];
  const float* bz  = (const float*)d_in[2];
  const float* Uz  = (const float*)d_in[3];
  const float* Wr  = (const float*)d_in[4];
  const float* br  = (const float*)d_in[5];
  const float* Ur  = (const float*)d_in[6];
  const float* Wh  = (const float*)d_in[7];
  const float* bh  = (const float*)d_in[8];
  const float* Uh  = (const float*)d_in[9];
  const float* fcw = (const float*)d_in[10];
  const float* fcb = (const float*)d_in[11];

  const size_t R = (size_t)BATCH * T_STEPS;          // 524288 rows
  const size_t bytesU = (size_t)NWU * 4;             // 288 KB
  const size_t bytesP = (size_t)NWP * 4;             // 96 KB
  const size_t projOff = bytesU + bytesP;            // 384 KB
  const size_t need32 = projOff + R * 384 * 4;       // ~768.4 MB
  const size_t need16 = projOff + R * 384 * 2;       // ~384.4 MB

  if (ws_size >= need16) {
    uint32_t* wpackU = (uint32_t*)d_ws;
    uint32_t* wpackP = (uint32_t*)((char*)d_ws + bytesU);
    void* proj = (void*)((char*)d_ws + projOff);
    hipLaunchKernelGGL(pack2, dim3((NWU + NWP) / 256), dim3(256), 0, stream,
                       Wz, Uz, Wr, Ur, Wh, Uh, wpackU, wpackP);
    if (ws_size >= need32) {
      hipLaunchKernelGGL((xproj<0>), dim3(1024), dim3(384), 0, stream,
                         x, bz, br, bh, wpackP, proj);
      hipLaunchKernelGGL((gru_persist2<0>), dim3(BATCH), dim3(512), 0, stream,
                         proj, bz + 128, br + 128, bh + 128, fcw, fcb, wpackU,
                         (float*)d_out);
    } else {
      hipLaunchKernelGGL((xproj<1>), dim3(1024), dim3(384), 0, stream,
                         x, bz, br, bh, wpackP, proj);
      hipLaunchKernelGGL((gru_persist2<1>), dim3(BATCH), dim3(512), 0, stream,
                         proj, bz + 128, br + 128, bh + 128, fcw, fcb, wpackU,
                         (float*)d_out);
    }
  } else {
    // fallback: round-2 all-in-one kernel (needs only 384 KB of ws)
    uint32_t* wpack = (uint32_t*)d_ws;
    hipLaunchKernelGGL(pack_weights, dim3(384), dim3(256), 0, stream,
                       Wz, Uz, Wr, Ur, Wh, Uh, wpack);
    hipLaunchKernelGGL(gru_persist, dim3(BATCH), dim3(512), 0, stream,
                       x, bz, br, bh, fcw, fcb, wpack, (float*)d_out);
  }
}